// Round 7
// baseline (222.793 us; speedup 1.0000x reference)
//
#include <hip/hip_runtime.h>

#define BATCH 4
#define SQL 2048
#define SKL 2048
#define DIM 512
#define NR 257
#define NRP 288
#define RAD 128

typedef __bf16 bf16x8 __attribute__((ext_vector_type(8)));
typedef float f32x4 __attribute__((ext_vector_type(4)));
typedef unsigned short u16;
typedef u16 u16x4 __attribute__((ext_vector_type(4)));
typedef u16 u16x8 __attribute__((ext_vector_type(8)));

__device__ inline u16 f2bf(float x) {
  union { float f; unsigned u; } v; v.f = x;
  unsigned r = v.u + 0x7FFF + ((v.u >> 16) & 1);   // RNE
  return (u16)(r >> 16);
}

__device__ inline void glds16(const u16* g, const u16* l) {
  __builtin_amdgcn_global_load_lds(
      (const __attribute__((address_space(1))) void*)g,
      (__attribute__((address_space(3))) void*)l, 16, 0, 0);
}

// ---------------- fused memory-only prep ----------------
__global__ __launch_bounds__(256) void prep_mem_kernel(const float* __restrict__ Q,
                                                       const float* __restrict__ K,
                                                       const float* __restrict__ V,
                                                       const float* __restrict__ rel,
                                                       u16x4* __restrict__ Qb,
                                                       u16x4* __restrict__ Kb,
                                                       u16* __restrict__ relb,
                                                       u16* __restrict__ Vt) {
  __shared__ float tile[32][33];
  int bid = blockIdx.x, tid = threadIdx.x;
  if (bid < 8192) {
    const f32x4* src = (bid < 4096) ? (const f32x4*)Q : (const f32x4*)K;
    u16x4* dst = (bid < 4096) ? Qb : Kb;
    int i = (bid & 4095) * 256 + tid;     // exactly covers 1048576 f32x4
    f32x4 f = src[i];
    u16x4 o;
#pragma unroll
    for (int e = 0; e < 4; e++) o[e] = f2bf(f[e]);
    dst[i] = o;
  } else if (bid < 8768) {
    int i = (bid - 8192) * 256 + tid;     // < NRP*DIM
    int r = i >> 9;                       // / 512
    relb[i] = (r < NR) ? f2bf(rel[i]) : (u16)0;
  } else {
    int t = bid - 8768;
    int b = t >> 10, rem = t & 1023;
    int k0 = (rem & 63) * 32, d0 = (rem >> 6) * 32;
    int tx = tid & 31, ty = tid >> 5;     // 32 x 8
#pragma unroll
    for (int r = 0; r < 4; r++)
      tile[ty + r * 8][tx] = V[((long)b * SKL + k0 + ty + r * 8) * DIM + d0 + tx];
    __syncthreads();
#pragma unroll
    for (int r = 0; r < 4; r++)
      Vt[((long)b * DIM + d0 + ty + r * 8) * SKL + k0 + tx] = f2bf(tile[tx][ty + r * 8]);
  }
}

// ---------------- energy + qrel combined launch ----------------
// bid < 256:  energy 256x256 tile (r5's proven 4-phase counted-vmcnt schedule)
// bid >= 256: qrel block (8 waves x 16 rows, one j-pair) — no dependency on
//             energy, both consume only prep outputs; qrel blocks backfill CUs
//             as energy blocks (1/CU at 128 KiB LDS) drain.
__global__ __launch_bounds__(512, 2) void energy_qrel_kernel(const u16* __restrict__ Qb,
                                                             const u16* __restrict__ Kb,
                                                             const u16* __restrict__ relb,
                                                             float* __restrict__ Qrel,
                                                             u16* __restrict__ S) {
  __shared__ u16 lds[65536];            // 128 KiB: [slot][A 16384 u16 | B 16384 u16]
  int bid = blockIdx.x;
  int tid = threadIdx.x;
  int wave = tid >> 6, lane = tid & 63;

  if (bid >= 256) {
    // ---------------- qrel: Qrel = Q @ rel^T ----------------
    int t = bid - 256;
    int xb = t & 63, jp = t >> 6;        // 64 row-panels x 9 j-pairs
    int m0 = xb * 128 + wave * 16;
    int j0 = jp * 2;
    int fr = lane & 15, fk = (lane >> 4) * 8;
    f32x4 acc[2] = {};
    const u16* qrow = Qb + (long)(m0 + fr) * DIM + fk;
    const u16* r0 = relb + (long)(j0 * 16 + fr) * DIM + fk;
    const u16* r1 = r0 + 16 * DIM;
    for (int k0 = 0; k0 < DIM; k0 += 32) {
      bf16x8 a = *(const bf16x8*)(qrow + k0);
      bf16x8 b0 = *(const bf16x8*)(r0 + k0);
      bf16x8 b1 = *(const bf16x8*)(r1 + k0);
      acc[0] = __builtin_amdgcn_mfma_f32_16x16x32_bf16(a, b0, acc[0], 0, 0, 0);
      acc[1] = __builtin_amdgcn_mfma_f32_16x16x32_bf16(a, b1, acc[1], 0, 0, 0);
    }
    int cr = (lane >> 4) * 4, cc = lane & 15;
#pragma unroll
    for (int t2 = 0; t2 < 2; t2++)
#pragma unroll
      for (int r = 0; r < 4; r++)
        Qrel[(long)(m0 + cr + r) * NRP + (j0 + t2) * 16 + cc] = acc[t2][r];
    return;
  }

  // ---------------- energy: S = bf16(Q K^T / sqrt(d)) ----------------
  int bx = bid & 7, by = (bid >> 3) & 7, b = bid >> 6;
  int m0 = by * 256, n0 = bx * 256;
  const u16* A = Qb + (long)b * SQL * DIM;
  const u16* Bp = Kb + (long)b * SKL * DIM;
  int wr = wave >> 2, wc = wave & 3;
  int fr = lane & 15, g = lane >> 4;
  int srow8 = lane >> 3;
  int scol = ((lane & 7) ^ srow8) * 8;  // inverse-swizzled source col (elems)

  f32x4 acc[4][2][4] = {};
  bf16x8 bB[4][2];

#define STA(slot, tt, q) do { \
    int rb_ = (q) * 32 + (wave & 3) * 8 + (wave >> 2) * 128; \
    glds16(A + (long)(m0 + rb_ + srow8) * DIM + (tt) * 64 + scol, \
           lds + (slot) * 32768 + rb_ * 64); \
  } while (0)
#define STB(slot, tt, p) do { \
    int rb_ = (p) * 64 + wave * 8; \
    glds16(Bp + (long)(n0 + rb_ + srow8) * DIM + (tt) * 64 + scol, \
           lds + (slot) * 32768 + 16384 + rb_ * 64); \
  } while (0)
#define LOADB(slot) do { \
    const u16* base_ = lds + (slot) * 32768 + 16384; \
    _Pragma("unroll") for (int jb = 0; jb < 4; jb++) { \
      _Pragma("unroll") for (int ks = 0; ks < 2; ks++) { \
        int row_ = wc * 64 + jb * 16 + fr; \
        int cb_ = (ks * 64 + g * 16) ^ ((row_ & 7) << 4); \
        bB[jb][ks] = *(const bf16x8*)(base_ + row_ * 64 + (cb_ >> 1)); \
      } \
    } \
  } while (0)
#define QUAD(slot, q) do { \
    const u16* baseA_ = lds + (slot) * 32768; \
    bf16x8 a_[2][2]; \
    _Pragma("unroll") for (int rb = 0; rb < 2; rb++) { \
      _Pragma("unroll") for (int ks = 0; ks < 2; ks++) { \
        int row_ = wr * 128 + (q) * 32 + rb * 16 + fr; \
        int cb_ = (ks * 64 + g * 16) ^ ((row_ & 7) << 4); \
        a_[rb][ks] = *(const bf16x8*)(baseA_ + row_ * 64 + (cb_ >> 1)); \
      } \
    } \
    __builtin_amdgcn_s_setprio(1); \
    _Pragma("unroll") for (int rb = 0; rb < 2; rb++) \
    _Pragma("unroll") for (int jb = 0; jb < 4; jb++) \
    _Pragma("unroll") for (int ks = 0; ks < 2; ks++) \
      acc[q][rb][jb] = __builtin_amdgcn_mfma_f32_16x16x32_bf16(a_[rb][ks], bB[jb][ks], acc[q][rb][jb], 0, 0, 0); \
    __builtin_amdgcn_s_setprio(0); \
  } while (0)

  const int NT = DIM / 64;  // 8
  STA(0, 0, 0); STA(0, 0, 1); STA(0, 0, 2); STA(0, 0, 3);
  STB(0, 0, 0); STB(0, 0, 1); STB(0, 0, 2); STB(0, 0, 3);
  STA(1, 1, 0); STA(1, 1, 1); STA(1, 1, 2);
  asm volatile("s_waitcnt vmcnt(3)" ::: "memory");
  asm volatile("s_barrier" ::: "memory");

  for (int t = 0; t < NT; ++t) {
    int cs = t & 1, ns = cs ^ 1;
    if (t + 1 < NT) {
      STA(ns, t + 1, 3);
      STB(ns, t + 1, 0); STB(ns, t + 1, 1); STB(ns, t + 1, 2); STB(ns, t + 1, 3);
    }
    LOADB(cs);
    QUAD(cs, 0);
    asm volatile("s_barrier" ::: "memory");
    if (t + 2 < NT) STA(cs, t + 2, 0);
    QUAD(cs, 1);
    asm volatile("s_barrier" ::: "memory");
    if (t + 2 < NT) STA(cs, t + 2, 1);
    QUAD(cs, 2);
    asm volatile("s_barrier" ::: "memory");
    if (t + 2 < NT) STA(cs, t + 2, 2);
    QUAD(cs, 3);
    if (t + 2 < NT) asm volatile("s_waitcnt vmcnt(3)" ::: "memory");
    else            asm volatile("s_waitcnt vmcnt(0)" ::: "memory");
    asm volatile("s_barrier" ::: "memory");
  }
#undef STA
#undef STB
#undef LOADB
#undef QUAD

  const float inv_norm = 0.04419417382415922f;  // 1/sqrt(512)
  int cr = (lane >> 4) * 4, cc = lane & 15;
#pragma unroll
  for (int q = 0; q < 4; q++)
#pragma unroll
    for (int rb = 0; rb < 2; rb++)
#pragma unroll
      for (int r = 0; r < 4; r++) {
        int row = m0 + wr * 128 + q * 32 + rb * 16 + cr + r;
        u16* sr = S + ((long)b * SQL + row) * SKL;
#pragma unroll
        for (int jb = 0; jb < 4; jb++)
          sr[n0 + wc * 64 + jb * 16 + cc] = f2bf(acc[q][rb][jb][r] * inv_norm);
      }
}

// ---------------- softmax (unchanged) ----------------
__global__ __launch_bounds__(256) void softmax_kernel(u16* __restrict__ S,
                                                      const float* __restrict__ Qrel,
                                                      float* __restrict__ attn) {
  long row = blockIdx.x;
  int q = (int)(row & (SQL - 1));
  u16* srow = S + row * SKL;
  float* arow = attn + row * SKL;
  int tid = threadIdx.x;
  int wave = tid >> 6, lane = tid & 63;
  __shared__ float qlds[NR];
  __shared__ float red[4];
  const float inv_norm = 0.04419417382415922f;
  const float* qr = Qrel + row * NRP;
  qlds[tid] = qr[tid] * inv_norm;          // tid 0..255
  if (tid == 0) qlds[256] = qr[256] * inv_norm;
  bf16x8 v = *(const bf16x8*)(srow + tid * 8);
  __syncthreads();
  float f[8];
  int kb = tid * 8 - q + RAD;
#pragma unroll
  for (int e = 0; e < 8; e++) {
    int idx = kb + e;
    idx = idx < 0 ? 0 : (idx > 2 * RAD ? 2 * RAD : idx);
    f[e] = (float)v[e] + qlds[idx];
  }
  float m = -1e30f;
#pragma unroll
  for (int e = 0; e < 8; e++) m = fmaxf(m, f[e]);
  for (int o = 32; o > 0; o >>= 1) m = fmaxf(m, __shfl_xor(m, o));
  if (lane == 0) red[wave] = m;
  __syncthreads();
  m = fmaxf(fmaxf(red[0], red[1]), fmaxf(red[2], red[3]));
  __syncthreads();
  float s = 0.0f;
  float e8[8];
#pragma unroll
  for (int e = 0; e < 8; e++) { e8[e] = __expf(f[e] - m); s += e8[e]; }
  for (int o = 32; o > 0; o >>= 1) s += __shfl_xor(s, o);
  if (lane == 0) red[wave] = s;
  __syncthreads();
  s = red[0] + red[1] + red[2] + red[3];
  float inv = 1.0f / s;
  f32x4 o0, o1;
  u16x8 pb;
#pragma unroll
  for (int e = 0; e < 4; e++) {
    float p = e8[e] * inv;
    o0[e] = p; pb[e] = f2bf(p);
  }
#pragma unroll
  for (int e = 0; e < 4; e++) {
    float p = e8[e + 4] * inv;
    o1[e] = p; pb[e + 4] = f2bf(p);
  }
  *(f32x4*)(arow + tid * 8) = o0;
  *(f32x4*)(arow + tid * 8 + 4) = o1;
  *(u16x8*)(srow + tid * 8) = pb;
}

// ---------------- Z = P @ V (unchanged from r6) ----------------
__global__ __launch_bounds__(512, 4) void z_kernel(const u16* __restrict__ S,
                                                   const u16* __restrict__ Vt,
                                                   float* __restrict__ Z) {
  __shared__ u16 lds[32768];            // 64 KiB: [slot 16384 u16][A 8192 | B 8192]
  int b = blockIdx.z;
  int m0 = blockIdx.y * 128;            // 16
  int n0 = blockIdx.x * 128;            // 4
  const u16* A = S + (long)b * SQL * SKL;
  const u16* Bp = Vt + (long)b * DIM * SKL;
  int tid = threadIdx.x;
  int wave = tid >> 6, lane = tid & 63;
  int wr = wave >> 2, wc = wave & 3;    // wave out: rows wr*64..+64, cols wc*32..+32
  int fr = lane & 15, g = lane >> 4;
  int srow8 = lane >> 3;
  int scol = ((lane & 7) ^ srow8) * 8;

  f32x4 acc[4][2] = {};

#define ZSTG(slot, tt) do { \
    _Pragma("unroll") for (int i_ = 0; i_ < 2; i_++) { \
      int r_ = wave * 16 + i_ * 8; \
      glds16(A + (long)(m0 + r_ + srow8) * SKL + (tt) * 64 + scol, \
             lds + (slot) * 16384 + r_ * 64); \
      glds16(Bp + (long)(n0 + r_ + srow8) * SKL + (tt) * 64 + scol, \
             lds + (slot) * 16384 + 8192 + r_ * 64); \
    } \
  } while (0)

  const int NT = SKL / 64;              // 32
  ZSTG(0, 0);
  ZSTG(1, 1);
  asm volatile("s_waitcnt vmcnt(4)" ::: "memory");
  asm volatile("s_barrier" ::: "memory");

  for (int t = 0; t < NT; ++t) {
    int cs = t & 1;
    const u16* baseA = lds + cs * 16384;
    const u16* baseB = lds + cs * 16384 + 8192;
    bf16x8 aF[4][2], bF[2][2];
#pragma unroll
    for (int rb = 0; rb < 4; rb++)
#pragma unroll
      for (int ks = 0; ks < 2; ks++) {
        int row = wr * 64 + rb * 16 + fr;
        int cb = (ks * 64 + g * 16) ^ ((row & 7) << 4);
        aF[rb][ks] = *(const bf16x8*)(baseA + row * 64 + (cb >> 1));
      }
#pragma unroll
    for (int jb = 0; jb < 2; jb++)
#pragma unroll
      for (int ks = 0; ks < 2; ks++) {
        int row = wc * 32 + jb * 16 + fr;
        int cb = (ks * 64 + g * 16) ^ ((row & 7) << 4);
        bF[jb][ks] = *(const bf16x8*)(baseB + row * 64 + (cb >> 1));
      }
    asm volatile("s_waitcnt lgkmcnt(0)" ::: "memory");
    __builtin_amdgcn_sched_barrier(0);
    asm volatile("s_barrier" ::: "memory");     // all waves done reading cs
    if (t + 2 < NT) ZSTG(cs, t + 2);            // overwrite cs for t+2
    __builtin_amdgcn_s_setprio(1);
#pragma unroll
    for (int rb = 0; rb < 4; rb++)
#pragma unroll
      for (int jb = 0; jb < 2; jb++)
#pragma unroll
        for (int ks = 0; ks < 2; ks++)
          acc[rb][jb] = __builtin_amdgcn_mfma_f32_16x16x32_bf16(aF[rb][ks], bF[jb][ks], acc[rb][jb], 0, 0, 0);
    __builtin_amdgcn_s_setprio(0);
    if (t + 2 < NT) asm volatile("s_waitcnt vmcnt(4)" ::: "memory");
    else            asm volatile("s_waitcnt vmcnt(0)" ::: "memory");
    asm volatile("s_barrier" ::: "memory");
  }
#undef ZSTG

  int cr = (lane >> 4) * 4, cc = lane & 15;
#pragma unroll
  for (int rb = 0; rb < 4; rb++)
#pragma unroll
    for (int r = 0; r < 4; r++) {
      int q = m0 + wr * 64 + rb * 16 + cr + r;
      float* zrow = Z + ((long)b * SQL + q) * DIM;
#pragma unroll
      for (int jb = 0; jb < 2; jb++)
        zrow[n0 + wc * 32 + jb * 16 + cc] = acc[rb][jb][r];
    }
}

// ---------------- launch ----------------

extern "C" void kernel_launch(void* const* d_in, const int* in_sizes, int n_in,
                              void* d_out, int out_size, void* d_ws, size_t ws_size,
                              hipStream_t stream) {
  const float* Q = (const float*)d_in[0];
  const float* K = (const float*)d_in[1];
  const float* V = (const float*)d_in[2];
  const float* rel = (const float*)d_in[3];
  float* attn = (float*)d_out;                       // [4][2048][2048]
  float* Z = attn + (long)BATCH * SQL * SKL;         // [4][2048][512]

  char* ws = (char*)d_ws;
  u16* Qb   = (u16*)ws;                    //  8 MiB  bf16 Q [b][q][d]
  u16* Kb   = (u16*)(ws + 8388608);        //  8 MiB  bf16 K [b][k][d]
  u16* Vt   = (u16*)(ws + 16777216);       //  8 MiB  bf16 V^T [b][d][k]
  u16* relb = (u16*)(ws + 25165824);       //  288 KiB bf16 rel padded [288][512]
  float* Qrel = (float*)(ws + 25460736);   //  9 MiB  fp32 Qrel [8192][288]
  u16* S    = (u16*)(ws + 34897920);       //  32 MiB bf16 scores/probs [b][q][k]

  prep_mem_kernel<<<12864, 256, 0, stream>>>(Q, K, V, rel, (u16x4*)Qb, (u16x4*)Kb, relb, Vt);
  energy_qrel_kernel<<<832, 512, 0, stream>>>(Qb, Kb, relb, Qrel, S);
  softmax_kernel<<<8192, 256, 0, stream>>>(S, Qrel, attn);
  z_kernel<<<dim3(4, 16, BATCH), 512, 0, stream>>>(S, Vt, Z);
}

// Round 8
// 212.654 us; speedup vs baseline: 1.0477x; 1.0477x over previous
//
#include <hip/hip_runtime.h>

#define BATCH 4
#define SQL 2048
#define SKL 2048
#define DIM 512
#define NR 257
#define NRP 288
#define RAD 128

typedef __bf16 bf16x8 __attribute__((ext_vector_type(8)));
typedef float f32x4 __attribute__((ext_vector_type(4)));
typedef unsigned short u16;
typedef u16 u16x4 __attribute__((ext_vector_type(4)));
typedef u16 u16x8 __attribute__((ext_vector_type(8)));

__device__ inline u16 f2bf(float x) {
  union { float f; unsigned u; } v; v.f = x;
  unsigned r = v.u + 0x7FFF + ((v.u >> 16) & 1);   // RNE
  return (u16)(r >> 16);
}

__device__ inline void glds16(const u16* g, const u16* l) {
  __builtin_amdgcn_global_load_lds(
      (const __attribute__((address_space(1))) void*)g,
      (__attribute__((address_space(3))) void*)l, 16, 0, 0);
}

// ---------------- fused memory-only prep ----------------
__global__ __launch_bounds__(256) void prep_mem_kernel(const float* __restrict__ Q,
                                                       const float* __restrict__ K,
                                                       const float* __restrict__ V,
                                                       const float* __restrict__ rel,
                                                       u16x4* __restrict__ Qb,
                                                       u16x4* __restrict__ Kb,
                                                       u16* __restrict__ relb,
                                                       u16* __restrict__ Vt) {
  __shared__ float tile[32][33];
  int bid = blockIdx.x, tid = threadIdx.x;
  if (bid < 8192) {
    const f32x4* src = (bid < 4096) ? (const f32x4*)Q : (const f32x4*)K;
    u16x4* dst = (bid < 4096) ? Qb : Kb;
    int i = (bid & 4095) * 256 + tid;     // exactly covers 1048576 f32x4
    f32x4 f = src[i];
    u16x4 o;
#pragma unroll
    for (int e = 0; e < 4; e++) o[e] = f2bf(f[e]);
    dst[i] = o;
  } else if (bid < 8768) {
    int i = (bid - 8192) * 256 + tid;     // < NRP*DIM
    int r = i >> 9;                       // / 512
    relb[i] = (r < NR) ? f2bf(rel[i]) : (u16)0;
  } else {
    int t = bid - 8768;
    int b = t >> 10, rem = t & 1023;
    int k0 = (rem & 63) * 32, d0 = (rem >> 6) * 32;
    int tx = tid & 31, ty = tid >> 5;     // 32 x 8
#pragma unroll
    for (int r = 0; r < 4; r++)
      tile[ty + r * 8][tx] = V[((long)b * SKL + k0 + ty + r * 8) * DIM + d0 + tx];
    __syncthreads();
#pragma unroll
    for (int r = 0; r < 4; r++)
      Vt[((long)b * DIM + d0 + ty + r * 8) * SKL + k0 + tx] = f2bf(tile[tx][ty + r * 8]);
  }
}

// ---------------- Qrel v2: Q read once, all live j-tiles per block ----------------
// 256 blocks x 256 threads; block = (row panel of 64) x (j-half).
// half 0: tiles 0..8, half 1: tiles 9..16. Tile 17 is all-pad (cols 272..287
// never read by softmax) -> skipped. relb (288 KB) stays L2-resident.
__global__ __launch_bounds__(256) void qrel_kernel(const u16* __restrict__ Qb,
                                                   const u16* __restrict__ relb,
                                                   float* __restrict__ Qrel) {
  int bid = blockIdx.x;
  int panel = bid >> 1, half = bid & 1;
  int tid = threadIdx.x;
  int wave = tid >> 6, lane = tid & 63;
  int m0 = panel * 64 + wave * 16;
  int fr = lane & 15, fk = (lane >> 4) * 8;
  const int J0 = half ? 9 : 0;
  const int NJ = half ? 8 : 9;
  f32x4 acc[9] = {};
  const u16* qrow = Qb + (long)(m0 + fr) * DIM + fk;
  const u16* rbase = relb + (long)(J0 * 16 + fr) * DIM + fk;
  for (int k0 = 0; k0 < DIM; k0 += 32) {
    bf16x8 a = *(const bf16x8*)(qrow + k0);
#pragma unroll
    for (int j = 0; j < 9; j++) {
      if (j < NJ) {
        bf16x8 b = *(const bf16x8*)(rbase + (long)j * 16 * DIM + k0);
        acc[j] = __builtin_amdgcn_mfma_f32_16x16x32_bf16(a, b, acc[j], 0, 0, 0);
      }
    }
  }
  int cr = (lane >> 4) * 4, cc = lane & 15;
#pragma unroll
  for (int j = 0; j < 9; j++) {
    if (j < NJ) {
#pragma unroll
      for (int r = 0; r < 4; r++)
        Qrel[(long)(m0 + cr + r) * NRP + (J0 + j) * 16 + cc] = acc[j][r];
    }
  }
}

// ---------------- energy: S = bf16(Q K^T / sqrt(d)) (r5's proven schedule) ----------------
__global__ __launch_bounds__(512, 2) void energy_kernel(const u16* __restrict__ Qb,
                                                        const u16* __restrict__ Kb,
                                                        u16* __restrict__ S) {
  __shared__ u16 lds[65536];            // 128 KiB: [slot][A 16384 u16 | B 16384 u16]
  int b = blockIdx.z;
  int m0 = blockIdx.y * 256, n0 = blockIdx.x * 256;
  const u16* A = Qb + (long)b * SQL * DIM;
  const u16* Bp = Kb + (long)b * SKL * DIM;
  int tid = threadIdx.x;
  int wave = tid >> 6, lane = tid & 63;
  int wr = wave >> 2, wc = wave & 3;
  int fr = lane & 15, g = lane >> 4;
  int srow8 = lane >> 3;
  int scol = ((lane & 7) ^ srow8) * 8;  // inverse-swizzled source col (elems)

  f32x4 acc[4][2][4] = {};
  bf16x8 bB[4][2];

#define STA(slot, tt, q) do { \
    int rb_ = (q) * 32 + (wave & 3) * 8 + (wave >> 2) * 128; \
    glds16(A + (long)(m0 + rb_ + srow8) * DIM + (tt) * 64 + scol, \
           lds + (slot) * 32768 + rb_ * 64); \
  } while (0)
#define STB(slot, tt, p) do { \
    int rb_ = (p) * 64 + wave * 8; \
    glds16(Bp + (long)(n0 + rb_ + srow8) * DIM + (tt) * 64 + scol, \
           lds + (slot) * 32768 + 16384 + rb_ * 64); \
  } while (0)
#define LOADB(slot) do { \
    const u16* base_ = lds + (slot) * 32768 + 16384; \
    _Pragma("unroll") for (int jb = 0; jb < 4; jb++) { \
      _Pragma("unroll") for (int ks = 0; ks < 2; ks++) { \
        int row_ = wc * 64 + jb * 16 + fr; \
        int cb_ = (ks * 64 + g * 16) ^ ((row_ & 7) << 4); \
        bB[jb][ks] = *(const bf16x8*)(base_ + row_ * 64 + (cb_ >> 1)); \
      } \
    } \
  } while (0)
#define QUAD(slot, q) do { \
    const u16* baseA_ = lds + (slot) * 32768; \
    bf16x8 a_[2][2]; \
    _Pragma("unroll") for (int rb = 0; rb < 2; rb++) { \
      _Pragma("unroll") for (int ks = 0; ks < 2; ks++) { \
        int row_ = wr * 128 + (q) * 32 + rb * 16 + fr; \
        int cb_ = (ks * 64 + g * 16) ^ ((row_ & 7) << 4); \
        a_[rb][ks] = *(const bf16x8*)(baseA_ + row_ * 64 + (cb_ >> 1)); \
      } \
    } \
    __builtin_amdgcn_s_setprio(1); \
    _Pragma("unroll") for (int rb = 0; rb < 2; rb++) \
    _Pragma("unroll") for (int jb = 0; jb < 4; jb++) \
    _Pragma("unroll") for (int ks = 0; ks < 2; ks++) \
      acc[q][rb][jb] = __builtin_amdgcn_mfma_f32_16x16x32_bf16(a_[rb][ks], bB[jb][ks], acc[q][rb][jb], 0, 0, 0); \
    __builtin_amdgcn_s_setprio(0); \
  } while (0)

  const int NT = DIM / 64;  // 8
  STA(0, 0, 0); STA(0, 0, 1); STA(0, 0, 2); STA(0, 0, 3);
  STB(0, 0, 0); STB(0, 0, 1); STB(0, 0, 2); STB(0, 0, 3);
  STA(1, 1, 0); STA(1, 1, 1); STA(1, 1, 2);
  asm volatile("s_waitcnt vmcnt(3)" ::: "memory");
  asm volatile("s_barrier" ::: "memory");

  for (int t = 0; t < NT; ++t) {
    int cs = t & 1, ns = cs ^ 1;
    if (t + 1 < NT) {
      STA(ns, t + 1, 3);
      STB(ns, t + 1, 0); STB(ns, t + 1, 1); STB(ns, t + 1, 2); STB(ns, t + 1, 3);
    }
    LOADB(cs);
    QUAD(cs, 0);
    asm volatile("s_barrier" ::: "memory");
    if (t + 2 < NT) STA(cs, t + 2, 0);
    QUAD(cs, 1);
    asm volatile("s_barrier" ::: "memory");
    if (t + 2 < NT) STA(cs, t + 2, 1);
    QUAD(cs, 2);
    asm volatile("s_barrier" ::: "memory");
    if (t + 2 < NT) STA(cs, t + 2, 2);
    QUAD(cs, 3);
    if (t + 2 < NT) asm volatile("s_waitcnt vmcnt(3)" ::: "memory");
    else            asm volatile("s_waitcnt vmcnt(0)" ::: "memory");
    asm volatile("s_barrier" ::: "memory");
  }
#undef STA
#undef STB
#undef LOADB
#undef QUAD

  const float inv_norm = 0.04419417382415922f;  // 1/sqrt(512)
  int cr = (lane >> 4) * 4, cc = lane & 15;
#pragma unroll
  for (int q = 0; q < 4; q++)
#pragma unroll
    for (int rb = 0; rb < 2; rb++)
#pragma unroll
      for (int r = 0; r < 4; r++) {
        int row = m0 + wr * 128 + q * 32 + rb * 16 + cr + r;
        u16* sr = S + ((long)b * SQL + row) * SKL;
#pragma unroll
        for (int jb = 0; jb < 4; jb++)
          sr[n0 + wc * 64 + jb * 16 + cc] = f2bf(acc[q][rb][jb][r] * inv_norm);
      }
}

// ---------------- softmax (unchanged) ----------------
__global__ __launch_bounds__(256) void softmax_kernel(u16* __restrict__ S,
                                                      const float* __restrict__ Qrel,
                                                      float* __restrict__ attn) {
  long row = blockIdx.x;
  int q = (int)(row & (SQL - 1));
  u16* srow = S + row * SKL;
  float* arow = attn + row * SKL;
  int tid = threadIdx.x;
  int wave = tid >> 6, lane = tid & 63;
  __shared__ float qlds[NR];
  __shared__ float red[4];
  const float inv_norm = 0.04419417382415922f;
  const float* qr = Qrel + row * NRP;
  qlds[tid] = qr[tid] * inv_norm;          // tid 0..255
  if (tid == 0) qlds[256] = qr[256] * inv_norm;
  bf16x8 v = *(const bf16x8*)(srow + tid * 8);
  __syncthreads();
  float f[8];
  int kb = tid * 8 - q + RAD;
#pragma unroll
  for (int e = 0; e < 8; e++) {
    int idx = kb + e;
    idx = idx < 0 ? 0 : (idx > 2 * RAD ? 2 * RAD : idx);
    f[e] = (float)v[e] + qlds[idx];
  }
  float m = -1e30f;
#pragma unroll
  for (int e = 0; e < 8; e++) m = fmaxf(m, f[e]);
  for (int o = 32; o > 0; o >>= 1) m = fmaxf(m, __shfl_xor(m, o));
  if (lane == 0) red[wave] = m;
  __syncthreads();
  m = fmaxf(fmaxf(red[0], red[1]), fmaxf(red[2], red[3]));
  __syncthreads();
  float s = 0.0f;
  float e8[8];
#pragma unroll
  for (int e = 0; e < 8; e++) { e8[e] = __expf(f[e] - m); s += e8[e]; }
  for (int o = 32; o > 0; o >>= 1) s += __shfl_xor(s, o);
  if (lane == 0) red[wave] = s;
  __syncthreads();
  s = red[0] + red[1] + red[2] + red[3];
  float inv = 1.0f / s;
  f32x4 o0, o1;
  u16x8 pb;
#pragma unroll
  for (int e = 0; e < 4; e++) {
    float p = e8[e] * inv;
    o0[e] = p; pb[e] = f2bf(p);
  }
#pragma unroll
  for (int e = 0; e < 4; e++) {
    float p = e8[e + 4] * inv;
    o1[e] = p; pb[e + 4] = f2bf(p);
  }
  *(f32x4*)(arow + tid * 8) = o0;
  *(f32x4*)(arow + tid * 8 + 4) = o1;
  *(u16x8*)(srow + tid * 8) = pb;
}

// ---------------- Z = P @ V (unchanged from r6) ----------------
__global__ __launch_bounds__(512, 4) void z_kernel(const u16* __restrict__ S,
                                                   const u16* __restrict__ Vt,
                                                   float* __restrict__ Z) {
  __shared__ u16 lds[32768];            // 64 KiB: [slot 16384 u16][A 8192 | B 8192]
  int b = blockIdx.z;
  int m0 = blockIdx.y * 128;            // 16
  int n0 = blockIdx.x * 128;            // 4
  const u16* A = S + (long)b * SQL * SKL;
  const u16* Bp = Vt + (long)b * DIM * SKL;
  int tid = threadIdx.x;
  int wave = tid >> 6, lane = tid & 63;
  int wr = wave >> 2, wc = wave & 3;    // wave out: rows wr*64..+64, cols wc*32..+32
  int fr = lane & 15, g = lane >> 4;
  int srow8 = lane >> 3;
  int scol = ((lane & 7) ^ srow8) * 8;

  f32x4 acc[4][2] = {};

#define ZSTG(slot, tt) do { \
    _Pragma("unroll") for (int i_ = 0; i_ < 2; i_++) { \
      int r_ = wave * 16 + i_ * 8; \
      glds16(A + (long)(m0 + r_ + srow8) * SKL + (tt) * 64 + scol, \
             lds + (slot) * 16384 + r_ * 64); \
      glds16(Bp + (long)(n0 + r_ + srow8) * SKL + (tt) * 64 + scol, \
             lds + (slot) * 16384 + 8192 + r_ * 64); \
    } \
  } while (0)

  const int NT = SKL / 64;              // 32
  ZSTG(0, 0);
  ZSTG(1, 1);
  asm volatile("s_waitcnt vmcnt(4)" ::: "memory");
  asm volatile("s_barrier" ::: "memory");

  for (int t = 0; t < NT; ++t) {
    int cs = t & 1;
    const u16* baseA = lds + cs * 16384;
    const u16* baseB = lds + cs * 16384 + 8192;
    bf16x8 aF[4][2], bF[2][2];
#pragma unroll
    for (int rb = 0; rb < 4; rb++)
#pragma unroll
      for (int ks = 0; ks < 2; ks++) {
        int row = wr * 64 + rb * 16 + fr;
        int cb = (ks * 64 + g * 16) ^ ((row & 7) << 4);
        aF[rb][ks] = *(const bf16x8*)(baseA + row * 64 + (cb >> 1));
      }
#pragma unroll
    for (int jb = 0; jb < 2; jb++)
#pragma unroll
      for (int ks = 0; ks < 2; ks++) {
        int row = wc * 32 + jb * 16 + fr;
        int cb = (ks * 64 + g * 16) ^ ((row & 7) << 4);
        bF[jb][ks] = *(const bf16x8*)(baseB + row * 64 + (cb >> 1));
      }
    asm volatile("s_waitcnt lgkmcnt(0)" ::: "memory");
    __builtin_amdgcn_sched_barrier(0);
    asm volatile("s_barrier" ::: "memory");     // all waves done reading cs
    if (t + 2 < NT) ZSTG(cs, t + 2);            // overwrite cs for t+2
    __builtin_amdgcn_s_setprio(1);
#pragma unroll
    for (int rb = 0; rb < 4; rb++)
#pragma unroll
      for (int jb = 0; jb < 2; jb++)
#pragma unroll
        for (int ks = 0; ks < 2; ks++)
          acc[rb][jb] = __builtin_amdgcn_mfma_f32_16x16x32_bf16(aF[rb][ks], bF[jb][ks], acc[rb][jb], 0, 0, 0);
    __builtin_amdgcn_s_setprio(0);
    if (t + 2 < NT) asm volatile("s_waitcnt vmcnt(4)" ::: "memory");
    else            asm volatile("s_waitcnt vmcnt(0)" ::: "memory");
    asm volatile("s_barrier" ::: "memory");
  }
#undef ZSTG

  int cr = (lane >> 4) * 4, cc = lane & 15;
#pragma unroll
  for (int rb = 0; rb < 4; rb++)
#pragma unroll
    for (int r = 0; r < 4; r++) {
      int q = m0 + wr * 64 + rb * 16 + cr + r;
      float* zrow = Z + ((long)b * SQL + q) * DIM;
#pragma unroll
      for (int jb = 0; jb < 2; jb++)
        zrow[n0 + wc * 32 + jb * 16 + cc] = acc[rb][jb][r];
    }
}

// ---------------- launch ----------------

extern "C" void kernel_launch(void* const* d_in, const int* in_sizes, int n_in,
                              void* d_out, int out_size, void* d_ws, size_t ws_size,
                              hipStream_t stream) {
  const float* Q = (const float*)d_in[0];
  const float* K = (const float*)d_in[1];
  const float* V = (const float*)d_in[2];
  const float* rel = (const float*)d_in[3];
  float* attn = (float*)d_out;                       // [4][2048][2048]
  float* Z = attn + (long)BATCH * SQL * SKL;         // [4][2048][512]

  char* ws = (char*)d_ws;
  u16* Qb   = (u16*)ws;                    //  8 MiB  bf16 Q [b][q][d]
  u16* Kb   = (u16*)(ws + 8388608);        //  8 MiB  bf16 K [b][k][d]
  u16* Vt   = (u16*)(ws + 16777216);       //  8 MiB  bf16 V^T [b][d][k]
  u16* relb = (u16*)(ws + 25165824);       //  288 KiB bf16 rel padded [288][512]
  float* Qrel = (float*)(ws + 25460736);   //  9 MiB  fp32 Qrel [8192][288]
  u16* S    = (u16*)(ws + 34897920);       //  32 MiB bf16 scores/probs [b][q][k]

  prep_mem_kernel<<<12864, 256, 0, stream>>>(Q, K, V, rel, (u16x4*)Qb, (u16x4*)Kb, relb, Vt);
  qrel_kernel<<<256, 256, 0, stream>>>(Qb, relb, Qrel);
  energy_kernel<<<dim3(8, 8, BATCH), 512, 0, stream>>>(Qb, Kb, S);
  softmax_kernel<<<8192, 256, 0, stream>>>(S, Qrel, attn);
  z_kernel<<<dim3(4, 16, BATCH), 512, 0, stream>>>(S, Vt, Z);
}

// Round 9
// 211.769 us; speedup vs baseline: 1.0521x; 1.0042x over previous
//
#include <hip/hip_runtime.h>

#define BATCH 4
#define SQL 2048
#define SKL 2048
#define DIM 512
#define NR 257
#define NRP 288
#define RAD 128

typedef __bf16 bf16x8 __attribute__((ext_vector_type(8)));
typedef float f32x4 __attribute__((ext_vector_type(4)));
typedef unsigned short u16;
typedef u16 u16x2 __attribute__((ext_vector_type(2)));
typedef u16 u16x4 __attribute__((ext_vector_type(4)));
typedef u16 u16x8 __attribute__((ext_vector_type(8)));

__device__ inline u16 f2bf(float x) {
  union { float f; unsigned u; } v; v.f = x;
  unsigned r = v.u + 0x7FFF + ((v.u >> 16) & 1);   // RNE
  return (u16)(r >> 16);
}

__device__ inline void glds16(const u16* g, const u16* l) {
  __builtin_amdgcn_global_load_lds(
      (const __attribute__((address_space(1))) void*)g,
      (__attribute__((address_space(3))) void*)l, 16, 0, 0);
}

// ---------------- fused memory-only prep ----------------
// blocks [0,4096):      cvt Q fp32 -> bf16
// blocks [4096,8192):   cvt K fp32 -> bf16
// blocks [8192,8768):   cvt rel fp32 -> bf16 padded [288][512]
// blocks [8768,10816):  transpose V [b][k][d] fp32 -> Vt [b][d][k] bf16
//                       (64-wide k tiles, u16x2 coalesced stores)
__global__ __launch_bounds__(256) void prep_mem_kernel(const float* __restrict__ Q,
                                                       const float* __restrict__ K,
                                                       const float* __restrict__ V,
                                                       const float* __restrict__ rel,
                                                       u16x4* __restrict__ Qb,
                                                       u16x4* __restrict__ Kb,
                                                       u16* __restrict__ relb,
                                                       u16* __restrict__ Vt) {
  __shared__ float tile[64][33];
  int bid = blockIdx.x, tid = threadIdx.x;
  if (bid < 8192) {
    const f32x4* src = (bid < 4096) ? (const f32x4*)Q : (const f32x4*)K;
    u16x4* dst = (bid < 4096) ? Qb : Kb;
    int i = (bid & 4095) * 256 + tid;     // exactly covers 1048576 f32x4
    f32x4 f = src[i];
    u16x4 o;
#pragma unroll
    for (int e = 0; e < 4; e++) o[e] = f2bf(f[e]);
    dst[i] = o;
  } else if (bid < 8768) {
    int i = (bid - 8192) * 256 + tid;     // < NRP*DIM
    int r = i >> 9;                       // / 512
    relb[i] = (r < NR) ? f2bf(rel[i]) : (u16)0;
  } else {
    int t = bid - 8768;
    int b = t >> 9, rem = t & 511;        // 512 blocks/batch
    int k0 = (rem & 31) * 64, d0 = (rem >> 5) * 32;
    int tx = tid & 31, ty = tid >> 5;     // 32 x 8
#pragma unroll
    for (int r = 0; r < 8; r++)
      tile[ty + r * 8][tx] = V[((long)b * SKL + k0 + ty + r * 8) * DIM + d0 + tx];
    __syncthreads();
#pragma unroll
    for (int r = 0; r < 4; r++) {
      int dl = ty + r * 8;
      u16x2 o;
      o[0] = f2bf(tile[2 * tx][dl]);
      o[1] = f2bf(tile[2 * tx + 1][dl]);
      *(u16x2*)(Vt + ((long)b * DIM + d0 + dl) * SKL + k0 + 2 * tx) = o;
    }
  }
}

// ---------------- Qrel v2: Q read once, all live j-tiles per block ----------------
__global__ __launch_bounds__(256) void qrel_kernel(const u16* __restrict__ Qb,
                                                   const u16* __restrict__ relb,
                                                   float* __restrict__ Qrel) {
  int bid = blockIdx.x;
  int panel = bid >> 1, half = bid & 1;
  int tid = threadIdx.x;
  int wave = tid >> 6, lane = tid & 63;
  int m0 = panel * 64 + wave * 16;
  int fr = lane & 15, fk = (lane >> 4) * 8;
  const int J0 = half ? 9 : 0;
  const int NJ = half ? 8 : 9;
  f32x4 acc[9] = {};
  const u16* qrow = Qb + (long)(m0 + fr) * DIM + fk;
  const u16* rbase = relb + (long)(J0 * 16 + fr) * DIM + fk;
  for (int k0 = 0; k0 < DIM; k0 += 32) {
    bf16x8 a = *(const bf16x8*)(qrow + k0);
#pragma unroll
    for (int j = 0; j < 9; j++) {
      if (j < NJ) {
        bf16x8 b = *(const bf16x8*)(rbase + (long)j * 16 * DIM + k0);
        acc[j] = __builtin_amdgcn_mfma_f32_16x16x32_bf16(a, b, acc[j], 0, 0, 0);
      }
    }
  }
  int cr = (lane >> 4) * 4, cc = lane & 15;
#pragma unroll
  for (int j = 0; j < 9; j++) {
    if (j < NJ) {
#pragma unroll
      for (int r = 0; r < 4; r++)
        Qrel[(long)(m0 + cr + r) * NRP + (J0 + j) * 16 + cc] = acc[j][r];
    }
  }
}

// ---------------- energy: S = bf16(Q K^T / sqrt(d)) ----------------
// r5's proven 4-phase counted-vmcnt schedule + T1 XCD-aware swizzle:
// each XCD gets 32 consecutive work items = half a batch (4 A-panels + 8
// B-panels = 3 MB, fits 4 MB L2) instead of a column scattered over 9 MB.
__global__ __launch_bounds__(512, 2) void energy_kernel(const u16* __restrict__ Qb,
                                                        const u16* __restrict__ Kb,
                                                        u16* __restrict__ S) {
  __shared__ u16 lds[65536];            // 128 KiB: [slot][A 16384 u16 | B 16384 u16]
  int flat = blockIdx.x + (blockIdx.y << 3) + (blockIdx.z << 6);  // 0..255
  int swz = ((flat & 7) << 5) + (flat >> 3);                       // T1 bijective
  int b = swz >> 6, rem = swz & 63;
  int m0 = (rem >> 3) * 256, n0 = (rem & 7) * 256;
  const u16* A = Qb + (long)b * SQL * DIM;
  const u16* Bp = Kb + (long)b * SKL * DIM;
  int tid = threadIdx.x;
  int wave = tid >> 6, lane = tid & 63;
  int wr = wave >> 2, wc = wave & 3;
  int fr = lane & 15, g = lane >> 4;
  int srow8 = lane >> 3;
  int scol = ((lane & 7) ^ srow8) * 8;  // inverse-swizzled source col (elems)

  f32x4 acc[4][2][4] = {};
  bf16x8 bB[4][2];

#define STA(slot, tt, q) do { \
    int rb_ = (q) * 32 + (wave & 3) * 8 + (wave >> 2) * 128; \
    glds16(A + (long)(m0 + rb_ + srow8) * DIM + (tt) * 64 + scol, \
           lds + (slot) * 32768 + rb_ * 64); \
  } while (0)
#define STB(slot, tt, p) do { \
    int rb_ = (p) * 64 + wave * 8; \
    glds16(Bp + (long)(n0 + rb_ + srow8) * DIM + (tt) * 64 + scol, \
           lds + (slot) * 32768 + 16384 + rb_ * 64); \
  } while (0)
#define LOADB(slot) do { \
    const u16* base_ = lds + (slot) * 32768 + 16384; \
    _Pragma("unroll") for (int jb = 0; jb < 4; jb++) { \
      _Pragma("unroll") for (int ks = 0; ks < 2; ks++) { \
        int row_ = wc * 64 + jb * 16 + fr; \
        int cb_ = (ks * 64 + g * 16) ^ ((row_ & 7) << 4); \
        bB[jb][ks] = *(const bf16x8*)(base_ + row_ * 64 + (cb_ >> 1)); \
      } \
    } \
  } while (0)
#define QUAD(slot, q) do { \
    const u16* baseA_ = lds + (slot) * 32768; \
    bf16x8 a_[2][2]; \
    _Pragma("unroll") for (int rb = 0; rb < 2; rb++) { \
      _Pragma("unroll") for (int ks = 0; ks < 2; ks++) { \
        int row_ = wr * 128 + (q) * 32 + rb * 16 + fr; \
        int cb_ = (ks * 64 + g * 16) ^ ((row_ & 7) << 4); \
        a_[rb][ks] = *(const bf16x8*)(baseA_ + row_ * 64 + (cb_ >> 1)); \
      } \
    } \
    __builtin_amdgcn_s_setprio(1); \
    _Pragma("unroll") for (int rb = 0; rb < 2; rb++) \
    _Pragma("unroll") for (int jb = 0; jb < 4; jb++) \
    _Pragma("unroll") for (int ks = 0; ks < 2; ks++) \
      acc[q][rb][jb] = __builtin_amdgcn_mfma_f32_16x16x32_bf16(a_[rb][ks], bB[jb][ks], acc[q][rb][jb], 0, 0, 0); \
    __builtin_amdgcn_s_setprio(0); \
  } while (0)

  const int NT = DIM / 64;  // 8
  STA(0, 0, 0); STA(0, 0, 1); STA(0, 0, 2); STA(0, 0, 3);
  STB(0, 0, 0); STB(0, 0, 1); STB(0, 0, 2); STB(0, 0, 3);
  STA(1, 1, 0); STA(1, 1, 1); STA(1, 1, 2);
  asm volatile("s_waitcnt vmcnt(3)" ::: "memory");
  asm volatile("s_barrier" ::: "memory");

  for (int t = 0; t < NT; ++t) {
    int cs = t & 1, ns = cs ^ 1;
    if (t + 1 < NT) {
      STA(ns, t + 1, 3);
      STB(ns, t + 1, 0); STB(ns, t + 1, 1); STB(ns, t + 1, 2); STB(ns, t + 1, 3);
    }
    LOADB(cs);
    QUAD(cs, 0);
    asm volatile("s_barrier" ::: "memory");
    if (t + 2 < NT) STA(cs, t + 2, 0);
    QUAD(cs, 1);
    asm volatile("s_barrier" ::: "memory");
    if (t + 2 < NT) STA(cs, t + 2, 1);
    QUAD(cs, 2);
    asm volatile("s_barrier" ::: "memory");
    if (t + 2 < NT) STA(cs, t + 2, 2);
    QUAD(cs, 3);
    if (t + 2 < NT) asm volatile("s_waitcnt vmcnt(3)" ::: "memory");
    else            asm volatile("s_waitcnt vmcnt(0)" ::: "memory");
    asm volatile("s_barrier" ::: "memory");
  }
#undef STA
#undef STB
#undef LOADB
#undef QUAD

  const float inv_norm = 0.04419417382415922f;  // 1/sqrt(512)
  int cr = (lane >> 4) * 4, cc = lane & 15;
#pragma unroll
  for (int q = 0; q < 4; q++)
#pragma unroll
    for (int rb = 0; rb < 2; rb++)
#pragma unroll
      for (int r = 0; r < 4; r++) {
        int row = m0 + wr * 128 + q * 32 + rb * 16 + cr + r;
        u16* sr = S + ((long)b * SQL + row) * SKL;
#pragma unroll
        for (int jb = 0; jb < 4; jb++)
          sr[n0 + wc * 64 + jb * 16 + cc] = f2bf(acc[q][rb][jb][r] * inv_norm);
      }
}

// ---------------- softmax (unchanged) ----------------
__global__ __launch_bounds__(256) void softmax_kernel(u16* __restrict__ S,
                                                      const float* __restrict__ Qrel,
                                                      float* __restrict__ attn) {
  long row = blockIdx.x;
  int q = (int)(row & (SQL - 1));
  u16* srow = S + row * SKL;
  float* arow = attn + row * SKL;
  int tid = threadIdx.x;
  int wave = tid >> 6, lane = tid & 63;
  __shared__ float qlds[NR];
  __shared__ float red[4];
  const float inv_norm = 0.04419417382415922f;
  const float* qr = Qrel + row * NRP;
  qlds[tid] = qr[tid] * inv_norm;          // tid 0..255
  if (tid == 0) qlds[256] = qr[256] * inv_norm;
  bf16x8 v = *(const bf16x8*)(srow + tid * 8);
  __syncthreads();
  float f[8];
  int kb = tid * 8 - q + RAD;
#pragma unroll
  for (int e = 0; e < 8; e++) {
    int idx = kb + e;
    idx = idx < 0 ? 0 : (idx > 2 * RAD ? 2 * RAD : idx);
    f[e] = (float)v[e] + qlds[idx];
  }
  float m = -1e30f;
#pragma unroll
  for (int e = 0; e < 8; e++) m = fmaxf(m, f[e]);
  for (int o = 32; o > 0; o >>= 1) m = fmaxf(m, __shfl_xor(m, o));
  if (lane == 0) red[wave] = m;
  __syncthreads();
  m = fmaxf(fmaxf(red[0], red[1]), fmaxf(red[2], red[3]));
  __syncthreads();
  float s = 0.0f;
  float e8[8];
#pragma unroll
  for (int e = 0; e < 8; e++) { e8[e] = __expf(f[e] - m); s += e8[e]; }
  for (int o = 32; o > 0; o >>= 1) s += __shfl_xor(s, o);
  if (lane == 0) red[wave] = s;
  __syncthreads();
  s = red[0] + red[1] + red[2] + red[3];
  float inv = 1.0f / s;
  f32x4 o0, o1;
  u16x8 pb;
#pragma unroll
  for (int e = 0; e < 4; e++) {
    float p = e8[e] * inv;
    o0[e] = p; pb[e] = f2bf(p);
  }
#pragma unroll
  for (int e = 0; e < 4; e++) {
    float p = e8[e + 4] * inv;
    o1[e] = p; pb[e + 4] = f2bf(p);
  }
  *(f32x4*)(arow + tid * 8) = o0;
  *(f32x4*)(arow + tid * 8 + 4) = o1;
  *(u16x8*)(srow + tid * 8) = pb;
}

// ---------------- Z = P @ V (unchanged from r6) ----------------
__global__ __launch_bounds__(512, 4) void z_kernel(const u16* __restrict__ S,
                                                   const u16* __restrict__ Vt,
                                                   float* __restrict__ Z) {
  __shared__ u16 lds[32768];            // 64 KiB: [slot 16384 u16][A 8192 | B 8192]
  int b = blockIdx.z;
  int m0 = blockIdx.y * 128;            // 16
  int n0 = blockIdx.x * 128;            // 4
  const u16* A = S + (long)b * SQL * SKL;
  const u16* Bp = Vt + (long)b * DIM * SKL;
  int tid = threadIdx.x;
  int wave = tid >> 6, lane = tid & 63;
  int wr = wave >> 2, wc = wave & 3;    // wave out: rows wr*64..+64, cols wc*32..+32
  int fr = lane & 15, g = lane >> 4;
  int srow8 = lane >> 3;
  int scol = ((lane & 7) ^ srow8) * 8;

  f32x4 acc[4][2] = {};

#define ZSTG(slot, tt) do { \
    _Pragma("unroll") for (int i_ = 0; i_ < 2; i_++) { \
      int r_ = wave * 16 + i_ * 8; \
      glds16(A + (long)(m0 + r_ + srow8) * SKL + (tt) * 64 + scol, \
             lds + (slot) * 16384 + r_ * 64); \
      glds16(Bp + (long)(n0 + r_ + srow8) * SKL + (tt) * 64 + scol, \
             lds + (slot) * 16384 + 8192 + r_ * 64); \
    } \
  } while (0)

  const int NT = SKL / 64;              // 32
  ZSTG(0, 0);
  ZSTG(1, 1);
  asm volatile("s_waitcnt vmcnt(4)" ::: "memory");
  asm volatile("s_barrier" ::: "memory");

  for (int t = 0; t < NT; ++t) {
    int cs = t & 1;
    const u16* baseA = lds + cs * 16384;
    const u16* baseB = lds + cs * 16384 + 8192;
    bf16x8 aF[4][2], bF[2][2];
#pragma unroll
    for (int rb = 0; rb < 4; rb++)
#pragma unroll
      for (int ks = 0; ks < 2; ks++) {
        int row = wr * 64 + rb * 16 + fr;
        int cb = (ks * 64 + g * 16) ^ ((row & 7) << 4);
        aF[rb][ks] = *(const bf16x8*)(baseA + row * 64 + (cb >> 1));
      }
#pragma unroll
    for (int jb = 0; jb < 2; jb++)
#pragma unroll
      for (int ks = 0; ks < 2; ks++) {
        int row = wc * 32 + jb * 16 + fr;
        int cb = (ks * 64 + g * 16) ^ ((row & 7) << 4);
        bF[jb][ks] = *(const bf16x8*)(baseB + row * 64 + (cb >> 1));
      }
    asm volatile("s_waitcnt lgkmcnt(0)" ::: "memory");
    __builtin_amdgcn_sched_barrier(0);
    asm volatile("s_barrier" ::: "memory");     // all waves done reading cs
    if (t + 2 < NT) ZSTG(cs, t + 2);            // overwrite cs for t+2
    __builtin_amdgcn_s_setprio(1);
#pragma unroll
    for (int rb = 0; rb < 4; rb++)
#pragma unroll
      for (int jb = 0; jb < 2; jb++)
#pragma unroll
        for (int ks = 0; ks < 2; ks++)
          acc[rb][jb] = __builtin_amdgcn_mfma_f32_16x16x32_bf16(aF[rb][ks], bF[jb][ks], acc[rb][jb], 0, 0, 0);
    __builtin_amdgcn_s_setprio(0);
    if (t + 2 < NT) asm volatile("s_waitcnt vmcnt(4)" ::: "memory");
    else            asm volatile("s_waitcnt vmcnt(0)" ::: "memory");
    asm volatile("s_barrier" ::: "memory");
  }
#undef ZSTG

  int cr = (lane >> 4) * 4, cc = lane & 15;
#pragma unroll
  for (int rb = 0; rb < 4; rb++)
#pragma unroll
    for (int r = 0; r < 4; r++) {
      int q = m0 + wr * 64 + rb * 16 + cr + r;
      float* zrow = Z + ((long)b * SQL + q) * DIM;
#pragma unroll
      for (int jb = 0; jb < 2; jb++)
        zrow[n0 + wc * 32 + jb * 16 + cc] = acc[rb][jb][r];
    }
}

// ---------------- launch ----------------

extern "C" void kernel_launch(void* const* d_in, const int* in_sizes, int n_in,
                              void* d_out, int out_size, void* d_ws, size_t ws_size,
                              hipStream_t stream) {
  const float* Q = (const float*)d_in[0];
  const float* K = (const float*)d_in[1];
  const float* V = (const float*)d_in[2];
  const float* rel = (const float*)d_in[3];
  float* attn = (float*)d_out;                       // [4][2048][2048]
  float* Z = attn + (long)BATCH * SQL * SKL;         // [4][2048][512]

  char* ws = (char*)d_ws;
  u16* Qb   = (u16*)ws;                    //  8 MiB  bf16 Q [b][q][d]
  u16* Kb   = (u16*)(ws + 8388608);        //  8 MiB  bf16 K [b][k][d]
  u16* Vt   = (u16*)(ws + 16777216);       //  8 MiB  bf16 V^T [b][d][k]
  u16* relb = (u16*)(ws + 25165824);       //  288 KiB bf16 rel padded [288][512]
  float* Qrel = (float*)(ws + 25460736);   //  9 MiB  fp32 Qrel [8192][288]
  u16* S    = (u16*)(ws + 34897920);       //  32 MiB bf16 scores/probs [b][q][k]

  prep_mem_kernel<<<10816, 256, 0, stream>>>(Q, K, V, rel, (u16x4*)Qb, (u16x4*)Kb, relb, Vt);
  qrel_kernel<<<256, 256, 0, stream>>>(Qb, relb, Qrel);
  energy_kernel<<<dim3(8, 8, BATCH), 512, 0, stream>>>(Qb, Kb, S);
  softmax_kernel<<<8192, 256, 0, stream>>>(S, Qrel, attn);
  z_kernel<<<dim3(4, 16, BATCH), 512, 0, stream>>>(S, Vt, Z);
}